// Round 6
// baseline (111.214 us; speedup 1.0000x reference)
//
#include <hip/hip_runtime.h>
#include <stdint.h>
#include <stddef.h>

#define NTOK 4096
#define DDIM 1024

typedef __attribute__((ext_vector_type(4))) float f32x4;
typedef __attribute__((ext_vector_type(8))) short s16x8;
typedef __attribute__((ext_vector_type(4))) unsigned short u16x4;
typedef __attribute__((ext_vector_type(4))) int i32x4;

__device__ __forceinline__ unsigned short f2bf(float f) {
  union { float f; unsigned u; } v; v.f = f;
  unsigned u = v.u + 0x7fffu + ((v.u >> 16) & 1u);
  return (unsigned short)(u >> 16);
}

__device__ __forceinline__ void gload_lds16(const void* g, void* l) {
  __builtin_amdgcn_global_load_lds(
      (const __attribute__((address_space(1))) void*)g,
      (__attribute__((address_space(3))) void*)l, 16, 0, 0);
}

#define VMWAIT(N) asm volatile("s_waitcnt vmcnt(" #N ")" ::: "memory")

// ---------- fused fp32->bf16 convert + lin dot ----------
__global__ void convlin_k(const float* __restrict__ x, const float* __restrict__ w,
                          const float* __restrict__ b0, const float* __restrict__ b1,
                          unsigned short* __restrict__ xb, float* __restrict__ lin) {
  int wv = threadIdx.x >> 6, lane = threadIdx.x & 63;
  int row = blockIdx.x * 4 + wv;
  const f32x4* xr = (const f32x4*)(x + (size_t)row * DDIM);
  const f32x4* w4 = (const f32x4*)w;
  u16x4* xb4 = (u16x4*)(xb + (size_t)row * DDIM);
  float s = 0.f;
  for (int j = lane; j < DDIM / 4; j += 64) {
    f32x4 a = xr[j], c = w4[j];
    s += a[0] * c[0] + a[1] * c[1] + a[2] * c[2] + a[3] * c[3];
    u16x4 o;
    o[0] = f2bf(a[0]); o[1] = f2bf(a[1]); o[2] = f2bf(a[2]); o[3] = f2bf(a[3]);
    xb4[j] = o;
  }
#pragma unroll
  for (int off = 32; off; off >>= 1) s += __shfl_down(s, off);
  if (lane == 0) lin[row] = s + b0[0] + (b1 ? b1[0] : 0.f);
}

// ---------- transpose-convert M fp32 -> Mt bf16 ----------
__global__ void transpose_bf16_k(const float* __restrict__ M,
                                 unsigned short* __restrict__ Mt) {
  __shared__ unsigned short tile[32][33];
  int tx = threadIdx.x, ty = threadIdx.y;
  int bx = blockIdx.x, by = blockIdx.y;
  int x = bx * 32 + tx;
  for (int i = ty; i < 32; i += 8)
    tile[i][tx] = f2bf(M[(size_t)(by * 32 + i) * DDIM + x]);
  __syncthreads();
  int ox = by * 32 + tx;
  for (int i = ty; i < 32; i += 8)
    Mt[(size_t)(bx * 32 + i) * DDIM + ox] = tile[tx][i];
}

// ---------- detect mask element width ----------
__global__ void detect_mask_k(const unsigned char* __restrict__ m, int* __restrict__ flag) {
  __shared__ int f;
  if (threadIdx.x == 0) f = 0;
  __syncthreads();
  int any = 0;
  for (int i = threadIdx.x; i < 4096; i += 256)
    if ((i & 3) && m[i]) any = 1;
  if (any) atomicOr(&f, 1);
  __syncthreads();
  if (threadIdx.x == 0) *flag = f;  // 1 => byte mask, 0 => int32 mask
}

// ---------- GEMM1: double-buffered 64x128 BT GEMM (unchanged, passing) ----------
__launch_bounds__(512, 4)
__global__ void gemm1_k(const unsigned short* __restrict__ A,
                        const unsigned short* __restrict__ B,
                        unsigned short* __restrict__ Cb) {
  constexpr int BM = 64, BN = 128, K = DDIM;
  constexpr int MF = 2, NF = 2, AI = 1, BI = 2;
  __shared__ unsigned short As[2][BM][64];
  __shared__ unsigned short Bs[2][BN][64];

  const int lin = blockIdx.x;
  const int cpx = gridDim.x >> 3;
  const int swz = (lin & 7) * cpx + (lin >> 3);
  const int bi = swz >> 3, bj = swz & 7;

  const int tid = threadIdx.x;
  const int wid = tid >> 6, lane = tid & 63;
  const int wr2 = wid >> 2, wc2 = wid & 3;
  const int l15 = lane & 15, l16 = lane >> 4;
  const int xm = lane & 7;

  const int srow0 = tid >> 3;
  const int swslot = (tid & 7) ^ (srow0 & 7);
  const unsigned short* Ag = A + (size_t)(bi * BM + srow0) * K + swslot * 8;
  const unsigned short* Bg = B + (size_t)(bj * BN + srow0) * K + swslot * 8;

  f32x4 acc[MF][NF] = {};

#define STAGE_G1(BUF, K0)                                                    \
  {                                                                          \
    _Pragma("unroll") for (int j = 0; j < AI; ++j)                           \
        gload_lds16(Ag + (size_t)(j * 64) * K + (K0),                        \
                    &As[BUF][0][0] + j * 4096 + wid * 512);                  \
    _Pragma("unroll") for (int j = 0; j < BI; ++j)                           \
        gload_lds16(Bg + (size_t)(j * 64) * K + (K0),                        \
                    &Bs[BUF][0][0] + j * 4096 + wid * 512);                  \
  }

  STAGE_G1(0, 0)
  VMWAIT(0);
  __builtin_amdgcn_s_barrier();

  for (int t = 0; t < 16; ++t) {
    const int cur = t & 1, nxt = cur ^ 1;
    if (t < 15) STAGE_G1(nxt, (t + 1) * 64)
#pragma unroll
    for (int kk = 0; kk < 2; ++kk) {
      s16x8 Areg[MF], Breg[NF];
#pragma unroll
      for (int m = 0; m < MF; ++m)
        Areg[m] = *(const s16x8*)&As[cur][wr2 * 32 + m * 16 + l15]
                                     [(((kk << 2) | l16) ^ xm) << 3];
#pragma unroll
      for (int n = 0; n < NF; ++n)
        Breg[n] = *(const s16x8*)&Bs[cur][wc2 * 32 + n * 16 + l15]
                                     [(((kk << 2) | l16) ^ xm) << 3];
      __builtin_amdgcn_s_setprio(1);
#pragma unroll
      for (int m = 0; m < MF; ++m)
#pragma unroll
        for (int n = 0; n < NF; ++n)
          acc[m][n] = __builtin_amdgcn_mfma_f32_16x16x32_bf16(
              Areg[m], Breg[n], acc[m][n], 0, 0, 0);
      __builtin_amdgcn_s_setprio(0);
    }
    VMWAIT(0);
    __builtin_amdgcn_s_barrier();
  }
#undef STAGE_G1

#pragma unroll
  for (int m = 0; m < MF; ++m) {
    int row0 = bi * BM + wr2 * 32 + m * 16 + 4 * l16;
#pragma unroll
    for (int n = 0; n < NF; ++n) {
      int col = bj * BN + wc2 * 32 + n * 16 + l15;
#pragma unroll
      for (int r = 0; r < 4; ++r)
        Cb[(size_t)(row0 + r) * DDIM + col] = f2bf(acc[m][n][r]);
    }
  }
}

// ---------- GEMM2: 256x128 tile, 3-buffer deep pipeline (T3+T4+T5) ----------
// 8 waves = 4(M) x 2(N); per-wave 64x64; BK=64; stage tile t+2 during t;
// one vmcnt(6)+barrier per K-tile; m97 XOR swizzle both sides.
__launch_bounds__(512, 2)
__global__ void gemm2_k(const unsigned short* __restrict__ A,
                        const unsigned short* __restrict__ B,
                        const float* __restrict__ linl,
                        const float* __restrict__ linr,
                        const void* __restrict__ mask,
                        const int* __restrict__ mflag,
                        float* __restrict__ scores,
                        float* __restrict__ xout) {
  constexpr int K = DDIM;
  // sA: 3 bufs x 256x64 (96 KB), sB: 3 bufs x 128x64 (48 KB); epi reuses as f32[256][128]
  __shared__ __align__(16) unsigned char smem[147456];
  unsigned short* sA = (unsigned short*)smem;            // 3*16384 elems
  unsigned short* sB = sA + 3 * 16384;                   // 3*8192 elems

  // XCD patch swizzle: per XCD an 8(bi) x 8(bj) patch, bijective over 512 wgs
  const int lin = blockIdx.x;
  const int xcd = lin & 7, w = lin >> 3;
  const int bi = (xcd & 1) * 8 + (w >> 3);
  const int bj = (xcd >> 1) * 8 + (w & 7);

  const int tid = threadIdx.x;
  const int wid = tid >> 6, lane = tid & 63;
  const int wm = wid >> 1, wn = wid & 1;  // 4 M-waves x 2 N-waves
  const int l15 = lane & 15, l16 = lane >> 4;
  const int xm = lane & 7;

  const int srow0 = tid >> 3;
  const int swslot = (tid & 7) ^ (srow0 & 7);
  const unsigned short* Ag = A + (size_t)(bi * 256 + srow0) * K + swslot * 8;
  const unsigned short* Bg = B + (size_t)(bj * 128 + srow0) * K + swslot * 8;

  f32x4 acc[4][4] = {};

#define STG_A(BUF, K0)                                                       \
  {                                                                          \
    _Pragma("unroll") for (int j = 0; j < 4; ++j)                            \
        gload_lds16(Ag + (size_t)(j * 64) * K + (K0),                        \
                    sA + (BUF)*16384 + j * 4096 + wid * 512);                \
  }
#define STG_B(BUF, K0)                                                       \
  {                                                                          \
    _Pragma("unroll") for (int j = 0; j < 2; ++j)                            \
        gload_lds16(Bg + (size_t)(j * 64) * K + (K0),                        \
                    sB + (BUF)*8192 + j * 4096 + wid * 512);                 \
  }

  // prologue: stage tiles 0 and 1 (12 loads); retire tile 0
  STG_A(0, 0) STG_B(0, 0)
  STG_A(1, 64) STG_B(1, 64)
  VMWAIT(6);
  __builtin_amdgcn_s_barrier();

  int cb = 0;  // buffer of tile t
  for (int t = 0; t < 16; ++t) {
    const int sb = (cb + 2 >= 3) ? cb - 1 : cb + 2;   // (t+2)%3
    const unsigned short* As0 = sA + cb * 16384;
    const unsigned short* Bs0 = sB + cb * 8192;
#pragma unroll
    for (int kk = 0; kk < 2; ++kk) {
      s16x8 Areg[4], Breg[4];
#pragma unroll
      for (int m = 0; m < 4; ++m)
        Areg[m] = *(const s16x8*)(As0 + (wm * 64 + m * 16 + l15) * 64 +
                                  ((((kk << 2) | l16) ^ xm) << 3));
#pragma unroll
      for (int n = 0; n < 4; ++n)
        Breg[n] = *(const s16x8*)(Bs0 + (wn * 64 + n * 16 + l15) * 64 +
                                  ((((kk << 2) | l16) ^ xm) << 3));
      if (t < 14) {
        if (kk == 0) { STG_A(sb, (t + 2) * 64) }
        else         { STG_B(sb, (t + 2) * 64) }
      }
      __builtin_amdgcn_s_setprio(1);
#pragma unroll
      for (int m = 0; m < 4; ++m)
#pragma unroll
        for (int n = 0; n < 4; ++n)
          acc[m][n] = __builtin_amdgcn_mfma_f32_16x16x32_bf16(
              Areg[m], Breg[n], acc[m][n], 0, 0, 0);
      __builtin_amdgcn_s_setprio(0);
    }
    if (t < 14) { VMWAIT(6); }
    else if (t == 14) { VMWAIT(0); }
    if (t < 15) __builtin_amdgcn_s_barrier();
    cb = (cb + 1 == 3) ? 0 : cb + 1;
  }
#undef STG_A
#undef STG_B

  // ---- epilogue: acc -> LDS f32[256][128] (XOR bit4 by row-bit2) -> stream ----
  __syncthreads();
  float* Cf = (float*)smem;
#pragma unroll
  for (int m = 0; m < 4; ++m) {
#pragma unroll
    for (int n = 0; n < 4; ++n) {
      int lc = wn * 64 + n * 16 + l15;
#pragma unroll
      for (int r = 0; r < 4; ++r) {
        int lr = wm * 64 + m * 16 + l16 * 4 + r;
        Cf[lr * 128 + (lc ^ (((lr >> 2) & 1) << 4))] = acc[m][n][r];
      }
    }
  }
  __syncthreads();

  const int mf = *mflag;
#pragma unroll
  for (int it = 0; it < 16; ++it) {
    int fid = it * 512 + tid;
    int lr = fid >> 5, sl = fid & 31;
    int c0 = sl << 2;
    int cs = c0 ^ (((lr >> 2) & 1) << 4);
    f32x4 v4 = *(const f32x4*)&Cf[lr * 128 + cs];
    int row = bi * 256 + lr;
    int colb = bj * 128 + c0;
    float ll = linl[row];
    f32x4 rr = *(const f32x4*)&linr[colb];
    size_t idx = (size_t)row * NTOK + colb;
    f32x4 o, sc;
    if (mf) {
      unsigned m4 = *(const unsigned*)((const unsigned char*)mask + idx);
#pragma unroll
      for (int e = 0; e < 4; ++e) {
        float v = v4[e] + ll + rr[e];
        v = v > 0.f ? v : 0.f;
        o[e] = v; sc[e] = ((m4 >> (8 * e)) & 255u) ? v : 0.f;
      }
    } else {
      i32x4 m4 = *(const i32x4*)((const int*)mask + idx);
#pragma unroll
      for (int e = 0; e < 4; ++e) {
        float v = v4[e] + ll + rr[e];
        v = v > 0.f ? v : 0.f;
        o[e] = v; sc[e] = m4[e] ? v : 0.f;
      }
    }
    *(f32x4*)&xout[idx] = o;
    *(f32x4*)&scores[idx] = sc;
  }
}

extern "C" void kernel_launch(void* const* d_in, const int* in_sizes, int n_in,
                              void* d_out, int out_size, void* d_ws, size_t ws_size,
                              hipStream_t stream) {
  const float* x_l    = (const float*)d_in[0];
  const float* x_r    = (const float*)d_in[1];
  const void*  maskp  = (const void*)d_in[2];
  const float* matrix = (const float*)d_in[3];
  const float* bias   = (const float*)d_in[4];
  const float* wl     = (const float*)d_in[5];
  const float* bl     = (const float*)d_in[6];
  const float* wr     = (const float*)d_in[7];
  const float* br     = (const float*)d_in[8];

  unsigned short* XLb = (unsigned short*)d_ws;
  unsigned short* XRb = XLb + (size_t)NTOK * DDIM;
  unsigned short* XMb = XRb + (size_t)NTOK * DDIM;
  unsigned short* Mtb = XMb + (size_t)NTOK * DDIM;
  float* lin_l = (float*)(Mtb + (size_t)DDIM * DDIM);
  float* lin_r = lin_l + NTOK;
  int* mflag = (int*)(lin_r + NTOK);

  float* scores = (float*)d_out;
  float* xout = scores + (size_t)NTOK * NTOK;

  convlin_k<<<NTOK / 4, 256, 0, stream>>>(x_l, wl, bl, bias, XLb, lin_l);
  convlin_k<<<NTOK / 4, 256, 0, stream>>>(x_r, wr, br, nullptr, XRb, lin_r);
  transpose_bf16_k<<<dim3(32, 32), dim3(32, 8), 0, stream>>>(matrix, Mtb);
  detect_mask_k<<<1, 256, 0, stream>>>((const unsigned char*)maskp, mflag);

  // GEMM1: XM = x_l @ M (64x128 tile, grid 512)
  gemm1_k<<<512, 512, 0, stream>>>(XLb, Mtb, XMb);

  // GEMM2: x = relu(XM @ XR^T + lin) , scores = mask?x:0  (256x128, 3-buf deep pipe)
  gemm2_k<<<512, 512, 0, stream>>>(XMb, XRb, lin_l, lin_r, maskp, mflag,
                                   scores, xout);
}

// Round 7
// 94.242 us; speedup vs baseline: 1.1801x; 1.1801x over previous
//
#include <hip/hip_runtime.h>
#include <stdint.h>
#include <stddef.h>

#define NTOK 4096
#define DDIM 1024

typedef __attribute__((ext_vector_type(4))) float f32x4;
typedef __attribute__((ext_vector_type(8))) short s16x8;
typedef __attribute__((ext_vector_type(4))) unsigned short u16x4;
typedef __attribute__((ext_vector_type(4))) int i32x4;

__device__ __forceinline__ unsigned short f2bf(float f) {
  union { float f; unsigned u; } v; v.f = f;
  unsigned u = v.u + 0x7fffu + ((v.u >> 16) & 1u);
  return (unsigned short)(u >> 16);
}

__device__ __forceinline__ void gload_lds16(const void* g, void* l) {
  __builtin_amdgcn_global_load_lds(
      (const __attribute__((address_space(1))) void*)g,
      (__attribute__((address_space(3))) void*)l, 16, 0, 0);
}

#define VMWAIT(N) asm volatile("s_waitcnt vmcnt(" #N ")" ::: "memory")

// ---------- fused fp32->bf16 convert + lin dot ----------
__global__ void convlin_k(const float* __restrict__ x, const float* __restrict__ w,
                          const float* __restrict__ b0, const float* __restrict__ b1,
                          unsigned short* __restrict__ xb, float* __restrict__ lin) {
  int wv = threadIdx.x >> 6, lane = threadIdx.x & 63;
  int row = blockIdx.x * 4 + wv;
  const f32x4* xr = (const f32x4*)(x + (size_t)row * DDIM);
  const f32x4* w4 = (const f32x4*)w;
  u16x4* xb4 = (u16x4*)(xb + (size_t)row * DDIM);
  float s = 0.f;
  for (int j = lane; j < DDIM / 4; j += 64) {
    f32x4 a = xr[j], c = w4[j];
    s += a[0] * c[0] + a[1] * c[1] + a[2] * c[2] + a[3] * c[3];
    u16x4 o;
    o[0] = f2bf(a[0]); o[1] = f2bf(a[1]); o[2] = f2bf(a[2]); o[3] = f2bf(a[3]);
    xb4[j] = o;
  }
#pragma unroll
  for (int off = 32; off; off >>= 1) s += __shfl_down(s, off);
  if (lane == 0) lin[row] = s + b0[0] + (b1 ? b1[0] : 0.f);
}

// ---------- transpose-convert M fp32 -> Mt bf16 ----------
__global__ void transpose_bf16_k(const float* __restrict__ M,
                                 unsigned short* __restrict__ Mt) {
  __shared__ unsigned short tile[32][33];
  int tx = threadIdx.x, ty = threadIdx.y;
  int bx = blockIdx.x, by = blockIdx.y;
  int x = bx * 32 + tx;
  for (int i = ty; i < 32; i += 8)
    tile[i][tx] = f2bf(M[(size_t)(by * 32 + i) * DDIM + x]);
  __syncthreads();
  int ox = by * 32 + tx;
  for (int i = ty; i < 32; i += 8)
    Mt[(size_t)(bx * 32 + i) * DDIM + ox] = tile[tx][i];
}

// ---------- detect mask element width ----------
__global__ void detect_mask_k(const unsigned char* __restrict__ m, int* __restrict__ flag) {
  __shared__ int f;
  if (threadIdx.x == 0) f = 0;
  __syncthreads();
  int any = 0;
  for (int i = threadIdx.x; i < 4096; i += 256)
    if ((i & 3) && m[i]) any = 1;
  if (any) atomicOr(&f, 1);
  __syncthreads();
  if (threadIdx.x == 0) *flag = f;  // 1 => byte mask, 0 => int32 mask
}

// ---------- GEMM1: double-buffered 64x128 BT GEMM (unchanged, passing) ----------
__launch_bounds__(512, 4)
__global__ void gemm1_k(const unsigned short* __restrict__ A,
                        const unsigned short* __restrict__ B,
                        unsigned short* __restrict__ Cb) {
  constexpr int BM = 64, BN = 128, K = DDIM;
  constexpr int MF = 2, NF = 2, AI = 1, BI = 2;
  __shared__ unsigned short As[2][BM][64];
  __shared__ unsigned short Bs[2][BN][64];

  const int lin = blockIdx.x;
  const int cpx = gridDim.x >> 3;
  const int swz = (lin & 7) * cpx + (lin >> 3);
  const int bi = swz >> 3, bj = swz & 7;

  const int tid = threadIdx.x;
  const int wid = tid >> 6, lane = tid & 63;
  const int wr2 = wid >> 2, wc2 = wid & 3;
  const int l15 = lane & 15, l16 = lane >> 4;
  const int xm = lane & 7;

  const int srow0 = tid >> 3;
  const int swslot = (tid & 7) ^ (srow0 & 7);
  const unsigned short* Ag = A + (size_t)(bi * BM + srow0) * K + swslot * 8;
  const unsigned short* Bg = B + (size_t)(bj * BN + srow0) * K + swslot * 8;

  f32x4 acc[MF][NF] = {};

#define STAGE_G1(BUF, K0)                                                    \
  {                                                                          \
    _Pragma("unroll") for (int j = 0; j < AI; ++j)                           \
        gload_lds16(Ag + (size_t)(j * 64) * K + (K0),                        \
                    &As[BUF][0][0] + j * 4096 + wid * 512);                  \
    _Pragma("unroll") for (int j = 0; j < BI; ++j)                           \
        gload_lds16(Bg + (size_t)(j * 64) * K + (K0),                        \
                    &Bs[BUF][0][0] + j * 4096 + wid * 512);                  \
  }

  STAGE_G1(0, 0)
  VMWAIT(0);
  __builtin_amdgcn_s_barrier();

  for (int t = 0; t < 16; ++t) {
    const int cur = t & 1, nxt = cur ^ 1;
    if (t < 15) STAGE_G1(nxt, (t + 1) * 64)
#pragma unroll
    for (int kk = 0; kk < 2; ++kk) {
      s16x8 Areg[MF], Breg[NF];
#pragma unroll
      for (int m = 0; m < MF; ++m)
        Areg[m] = *(const s16x8*)&As[cur][wr2 * 32 + m * 16 + l15]
                                     [(((kk << 2) | l16) ^ xm) << 3];
#pragma unroll
      for (int n = 0; n < NF; ++n)
        Breg[n] = *(const s16x8*)&Bs[cur][wc2 * 32 + n * 16 + l15]
                                     [(((kk << 2) | l16) ^ xm) << 3];
      __builtin_amdgcn_s_setprio(1);
#pragma unroll
      for (int m = 0; m < MF; ++m)
#pragma unroll
        for (int n = 0; n < NF; ++n)
          acc[m][n] = __builtin_amdgcn_mfma_f32_16x16x32_bf16(
              Areg[m], Breg[n], acc[m][n], 0, 0, 0);
      __builtin_amdgcn_s_setprio(0);
    }
    VMWAIT(0);
    __builtin_amdgcn_s_barrier();
  }
#undef STAGE_G1

#pragma unroll
  for (int m = 0; m < MF; ++m) {
    int row0 = bi * BM + wr2 * 32 + m * 16 + 4 * l16;
#pragma unroll
    for (int n = 0; n < NF; ++n) {
      int col = bj * BN + wc2 * 32 + n * 16 + l15;
#pragma unroll
      for (int r = 0; r < 4; ++r)
        Cb[(size_t)(row0 + r) * DDIM + col] = f2bf(acc[m][n][r]);
    }
  }
}

// ---------- GEMM2: 128x128, BK=32, 5-buffer deep pipeline, 2 blocks/CU ----------
// 8 waves = 2(M) x 4(N), 64x32 per wave; stage tile t+4 during t; one
// vmcnt(6)+barrier per tile; never drains until tail. LDS = 80KB exactly.
__launch_bounds__(512, 4)
__global__ void gemm2_k(const unsigned short* __restrict__ A,
                        const unsigned short* __restrict__ B,
                        const float* __restrict__ linl,
                        const float* __restrict__ linr,
                        const void* __restrict__ mask,
                        const int* __restrict__ mflag,
                        float* __restrict__ scores,
                        float* __restrict__ xout) {
  constexpr int K = DDIM;
  // 5 bufs x (A 128x32 + B 128x32) bf16 = 5*16KB = 80KB
  __shared__ __align__(16) unsigned short sAB[5 * 4096 * 2];
  unsigned short* sA = sAB;
  unsigned short* sB = sAB + 5 * 4096;

  // XCD patch swizzle: 32 patches of 4(bi) x 8(bj) blocks (bijective, grid 1024)
  const int lin = blockIdx.x;
  const int xcd = lin & 7, s = lin >> 3;
  const int p = (s >> 5) * 8 + xcd;
  const int w = s & 31;
  const int bi = (p >> 2) * 4 + (w >> 3);
  const int bj = (p & 3) * 8 + (w & 7);

  const int tid = threadIdx.x;
  const int wid = tid >> 6, lane = tid & 63;
  const int wr2 = wid >> 2, wc2 = wid & 3;   // 2(M) x 4(N)
  const int l15 = lane & 15, l16 = lane >> 4;
  const int xs = (l15 >> 1) & 3;             // read-side slot swizzle

  // staging: thread tid covers row=tid>>2, k-slot tid&3 (8 elems); pre-swizzle src
  const int srow0 = tid >> 2;
  const int swslot = (tid & 3) ^ ((srow0 >> 1) & 3);
  const unsigned short* Ag = A + (size_t)(bi * 128 + srow0) * K + swslot * 8;
  const unsigned short* Bg = B + (size_t)(bj * 128 + srow0) * K + swslot * 8;

  f32x4 acc[4][2] = {};

#define STG2(BUF, K0)                                                        \
  {                                                                          \
    gload_lds16(Ag + (K0), sA + (BUF)*4096 + wid * 512);                     \
    gload_lds16(Bg + (K0), sB + (BUF)*4096 + wid * 512);                     \
  }

#define T_BODY(DOSTG, K0S, WAITSTMT, DOBAR)                                  \
  {                                                                          \
    const unsigned short* As0 = sA + cb * 4096;                              \
    const unsigned short* Bs0 = sB + cb * 4096;                              \
    s16x8 Areg[4], Breg[2];                                                  \
    _Pragma("unroll") for (int m = 0; m < 4; ++m)                            \
        Areg[m] = *(const s16x8*)(As0 + (wr2 * 64 + m * 16 + l15) * 32 +     \
                                  ((l16 ^ xs) << 3));                        \
    _Pragma("unroll") for (int n = 0; n < 2; ++n)                            \
        Breg[n] = *(const s16x8*)(Bs0 + (wc2 * 32 + n * 16 + l15) * 32 +     \
                                  ((l16 ^ xs) << 3));                        \
    if (DOSTG) { STG2(sb, K0S) }                                             \
    __builtin_amdgcn_s_setprio(1);                                           \
    _Pragma("unroll") for (int m = 0; m < 4; ++m)                            \
        _Pragma("unroll") for (int n = 0; n < 2; ++n)                        \
            acc[m][n] = __builtin_amdgcn_mfma_f32_16x16x32_bf16(             \
                Areg[m], Breg[n], acc[m][n], 0, 0, 0);                       \
    __builtin_amdgcn_s_setprio(0);                                           \
    WAITSTMT                                                                 \
    if (DOBAR) __builtin_amdgcn_s_barrier();                                 \
    cb = (cb + 1 == 5) ? 0 : cb + 1;                                         \
  }

  // prologue: stage tiles 0..3 (8 loads); retire tile 0
  STG2(0, 0) STG2(1, 32) STG2(2, 64) STG2(3, 96)
  VMWAIT(6);
  __builtin_amdgcn_s_barrier();

  int cb = 0;
  for (int t = 0; t < 28; ++t) {
    const int sb = cb ? cb - 1 : 4;  // (cb+4)%5
    T_BODY(1, (t + 4) * 32, VMWAIT(6);, 1)
  }
  {
    const int sb = 0;
    (void)sb;
    T_BODY(0, 0, VMWAIT(4);, 1)   // t=28
    T_BODY(0, 0, VMWAIT(2);, 1)   // t=29
    T_BODY(0, 0, VMWAIT(0);, 1)   // t=30
    T_BODY(0, 0, , 0)             // t=31
  }
#undef T_BODY
#undef STG2

  // ---- epilogue: acc -> LDS f32[128][128] (XOR bit4 by row-bit2) -> stream ----
  __syncthreads();
  float* Cf = (float*)sAB;
#pragma unroll
  for (int m = 0; m < 4; ++m) {
#pragma unroll
    for (int n = 0; n < 2; ++n) {
      int lc = wc2 * 32 + n * 16 + l15;
#pragma unroll
      for (int r = 0; r < 4; ++r) {
        int lr = wr2 * 64 + m * 16 + l16 * 4 + r;
        Cf[lr * 128 + (lc ^ (((lr >> 2) & 1) << 4))] = acc[m][n][r];
      }
    }
  }
  __syncthreads();

  const int mf = *mflag;
#pragma unroll
  for (int it = 0; it < 8; ++it) {
    int fid = it * 512 + tid;
    int lr = fid >> 5, sl = fid & 31;
    int c0 = sl << 2;
    int cs = c0 ^ (((lr >> 2) & 1) << 4);
    f32x4 v4 = *(const f32x4*)&Cf[lr * 128 + cs];
    int row = bi * 128 + lr;
    int colb = bj * 128 + c0;
    float ll = linl[row];
    f32x4 rr = *(const f32x4*)&linr[colb];
    size_t idx = (size_t)row * NTOK + colb;
    f32x4 o, sc;
    if (mf) {
      unsigned m4 = *(const unsigned*)((const unsigned char*)mask + idx);
#pragma unroll
      for (int e = 0; e < 4; ++e) {
        float v = v4[e] + ll + rr[e];
        v = v > 0.f ? v : 0.f;
        o[e] = v; sc[e] = ((m4 >> (8 * e)) & 255u) ? v : 0.f;
      }
    } else {
      i32x4 m4 = *(const i32x4*)((const int*)mask + idx);
#pragma unroll
      for (int e = 0; e < 4; ++e) {
        float v = v4[e] + ll + rr[e];
        v = v > 0.f ? v : 0.f;
        o[e] = v; sc[e] = m4[e] ? v : 0.f;
      }
    }
    *(f32x4*)&xout[idx] = o;
    *(f32x4*)&scores[idx] = sc;
  }
}

extern "C" void kernel_launch(void* const* d_in, const int* in_sizes, int n_in,
                              void* d_out, int out_size, void* d_ws, size_t ws_size,
                              hipStream_t stream) {
  const float* x_l    = (const float*)d_in[0];
  const float* x_r    = (const float*)d_in[1];
  const void*  maskp  = (const void*)d_in[2];
  const float* matrix = (const float*)d_in[3];
  const float* bias   = (const float*)d_in[4];
  const float* wl     = (const float*)d_in[5];
  const float* bl     = (const float*)d_in[6];
  const float* wr     = (const float*)d_in[7];
  const float* br     = (const float*)d_in[8];

  unsigned short* XLb = (unsigned short*)d_ws;
  unsigned short* XRb = XLb + (size_t)NTOK * DDIM;
  unsigned short* XMb = XRb + (size_t)NTOK * DDIM;
  unsigned short* Mtb = XMb + (size_t)NTOK * DDIM;
  float* lin_l = (float*)(Mtb + (size_t)DDIM * DDIM);
  float* lin_r = lin_l + NTOK;
  int* mflag = (int*)(lin_r + NTOK);

  float* scores = (float*)d_out;
  float* xout = scores + (size_t)NTOK * NTOK;

  convlin_k<<<NTOK / 4, 256, 0, stream>>>(x_l, wl, bl, bias, XLb, lin_l);
  convlin_k<<<NTOK / 4, 256, 0, stream>>>(x_r, wr, br, nullptr, XRb, lin_r);
  transpose_bf16_k<<<dim3(32, 32), dim3(32, 8), 0, stream>>>(matrix, Mtb);
  detect_mask_k<<<1, 256, 0, stream>>>((const unsigned char*)maskp, mflag);

  // GEMM1: XM = x_l @ M (64x128 tile, grid 512)
  gemm1_k<<<512, 512, 0, stream>>>(XLb, Mtb, XMb);

  // GEMM2: x = relu(XM @ XR^T + lin), scores = mask?x:0
  gemm2_k<<<1024, 512, 0, stream>>>(XMb, XRb, lin_l, lin_r, maskp, mflag,
                                    scores, xout);
}